// Round 1
// baseline (619.709 us; speedup 1.0000x reference)
//
#include <hip/hip_runtime.h>
#include <hip/hip_bf16.h>

#define B_   4
#define L_   2048
#define D_   1024
#define H_   16
#define DH_  64
#define DFF_ 4096
#define M_   (B_ * L_)   // 8192

typedef __attribute__((ext_vector_type(8))) short bf16x8;
typedef __attribute__((ext_vector_type(4))) float f32x4;

// ---------------- mask storage-width detection ----------------
// bool mask may be stored as u8 / i32 / f32 depending on harness conversion.
// Classify from first 2048 words (deterministic).
__global__ void mask_mode_detect(const unsigned int* __restrict__ m,
                                 int* __restrict__ mode) {
  __shared__ int flags[2];
  if (threadIdx.x < 2) flags[threadIdx.x] = 0;
  __syncthreads();
  int nf32 = 0, n01 = 0;
  for (int i = threadIdx.x; i < 2048; i += 256) {
    unsigned w = m[i];
    if (w != 0u && w != 0x3f800000u) nf32 = 1;
    if (w > 1u) n01 = 1;
  }
  if (nf32) atomicOr(&flags[0], 1);
  if (n01)  atomicOr(&flags[1], 1);
  __syncthreads();
  if (threadIdx.x == 0)
    *mode = (!flags[0]) ? 0 : ((!flags[1]) ? 1 : 2);  // 0=f32 1=i32 2=u8
}

// ---------------- f32 -> bf16 convert (vectorized) ----------------
__global__ void cvt_f32_bf16(const float4* __restrict__ in,
                             ushort4* __restrict__ out, int n4) {
  int i = blockIdx.x * 256 + threadIdx.x;
  if (i >= n4) return;
  float4 v = in[i];
  __hip_bfloat16 a = __float2bfloat16(v.x);
  __hip_bfloat16 b = __float2bfloat16(v.y);
  __hip_bfloat16 c = __float2bfloat16(v.z);
  __hip_bfloat16 d = __float2bfloat16(v.w);
  ushort4 o;
  o.x = *reinterpret_cast<unsigned short*>(&a);
  o.y = *reinterpret_cast<unsigned short*>(&b);
  o.z = *reinterpret_cast<unsigned short*>(&c);
  o.w = *reinterpret_cast<unsigned short*>(&d);
  out[i] = o;
}

// ---------------- W[K][N] f32 -> Wt[N][K] bf16 ----------------
__global__ void transpose_cvt(const float* __restrict__ W,
                              __hip_bfloat16* __restrict__ Wt, int K, int N) {
  __shared__ float t[32][33];
  const int n0 = blockIdx.x * 32, k0 = blockIdx.y * 32;
  const int tx = threadIdx.x, ty = threadIdx.y;  // 32x8
#pragma unroll
  for (int i = 0; i < 4; ++i)
    t[ty + i * 8][tx] = W[(size_t)(k0 + ty + i * 8) * N + n0 + tx];
  __syncthreads();
#pragma unroll
  for (int i = 0; i < 4; ++i)
    Wt[(size_t)(n0 + ty + i * 8) * K + k0 + tx] =
        __float2bfloat16(t[tx][ty + i * 8]);
}

// ---------------- V[b*L+l][D] bf16 -> VT[(b*D+d)][L] bf16 ----------------
__global__ void transpose_v(const __hip_bfloat16* __restrict__ Vin,
                            __hip_bfloat16* __restrict__ Vt) {
  __shared__ __hip_bfloat16 t[32][33];
  const int l0 = blockIdx.x * 32, d0 = blockIdx.y * 32, b = blockIdx.z;
  const int tx = threadIdx.x, ty = threadIdx.y;
#pragma unroll
  for (int i = 0; i < 4; ++i)
    t[ty + i * 8][tx] = Vin[(size_t)(b * L_ + l0 + ty + i * 8) * D_ + d0 + tx];
  __syncthreads();
#pragma unroll
  for (int i = 0; i < 4; ++i) {
    int d = d0 + ty + i * 8;
    Vt[(size_t)(b * D_ + d) * L_ + l0 + tx] = t[tx][ty + i * 8];
  }
}

// ---------------- GEMM: C[M,N] = A[M,K](bf16) * Bt[N,K]^T + bias ----------
// EP 0: bf16 out = acc+bias ; EP 1: bf16 out = relu(acc+bias)
// EP 2: f32 out = acc+bias+res
template <int EP>
__global__ __launch_bounds__(256) void gemm_bt(
    const __hip_bfloat16* __restrict__ A, const __hip_bfloat16* __restrict__ Bt,
    const float* __restrict__ bias, const float* __restrict__ res,
    void* __restrict__ out, int M, int N, int K) {
  __shared__ __hip_bfloat16 As[128][40];
  __shared__ __hip_bfloat16 Bs[128][40];
  const int tid = threadIdx.x;
  const int lane = tid & 63;
  const int w = tid >> 6;
  const int wm = w >> 1, wn = w & 1;
  const int bm = blockIdx.x * 128;
  const int bn = blockIdx.y * 128;
  const int r16 = lane & 15;
  const int hi = lane >> 4;
  const int koff = hi * 8;
  const int lrow = tid >> 2;         // 0..63
  const int lcol = (tid & 3) * 8;    // 0,8,16,24

  f32x4 acc[4][4];
#pragma unroll
  for (int m = 0; m < 4; ++m)
#pragma unroll
    for (int n = 0; n < 4; ++n) acc[m][n] = (f32x4){0.f, 0.f, 0.f, 0.f};

  for (int k0 = 0; k0 < K; k0 += 32) {
    __syncthreads();
    int4 va0 = *reinterpret_cast<const int4*>(&A[(size_t)(bm + lrow) * K + k0 + lcol]);
    int4 va1 = *reinterpret_cast<const int4*>(&A[(size_t)(bm + lrow + 64) * K + k0 + lcol]);
    int4 vb0 = *reinterpret_cast<const int4*>(&Bt[(size_t)(bn + lrow) * K + k0 + lcol]);
    int4 vb1 = *reinterpret_cast<const int4*>(&Bt[(size_t)(bn + lrow + 64) * K + k0 + lcol]);
    *reinterpret_cast<int4*>(&As[lrow][lcol]) = va0;
    *reinterpret_cast<int4*>(&As[lrow + 64][lcol]) = va1;
    *reinterpret_cast<int4*>(&Bs[lrow][lcol]) = vb0;
    *reinterpret_cast<int4*>(&Bs[lrow + 64][lcol]) = vb1;
    __syncthreads();

    bf16x8 af[4], bfr[4];
#pragma unroll
    for (int m = 0; m < 4; ++m)
      af[m] = *reinterpret_cast<const bf16x8*>(&As[wm * 64 + m * 16 + r16][koff]);
#pragma unroll
    for (int n = 0; n < 4; ++n)
      bfr[n] = *reinterpret_cast<const bf16x8*>(&Bs[wn * 64 + n * 16 + r16][koff]);
#pragma unroll
    for (int m = 0; m < 4; ++m)
#pragma unroll
      for (int n = 0; n < 4; ++n)
        acc[m][n] = __builtin_amdgcn_mfma_f32_16x16x32_bf16(af[m], bfr[n],
                                                            acc[m][n], 0, 0, 0);
  }

  const int rg = hi * 4;
#pragma unroll
  for (int m = 0; m < 4; ++m) {
#pragma unroll
    for (int n = 0; n < 4; ++n) {
      const int col = bn + wn * 64 + n * 16 + r16;
      const float bv = bias[col];
#pragma unroll
      for (int r = 0; r < 4; ++r) {
        const int row = bm + wm * 64 + m * 16 + rg + r;
        const size_t idx = (size_t)row * N + col;
        float v = acc[m][n][r] + bv;
        if (EP == 0) {
          ((__hip_bfloat16*)out)[idx] = __float2bfloat16(v);
        } else if (EP == 1) {
          ((__hip_bfloat16*)out)[idx] = __float2bfloat16(v > 0.f ? v : 0.f);
        } else {
          ((float*)out)[idx] = v + res[idx];
        }
      }
    }
  }
}

// ---------------- flash attention ----------------
// grid: (B*H, L/128); block 256 = 4 waves, each wave owns 32 q rows.
__global__ __launch_bounds__(256) void attn_kernel(
    const __hip_bfloat16* __restrict__ Qg, const __hip_bfloat16* __restrict__ Kg,
    const __hip_bfloat16* __restrict__ VTg,  // [(b*D + h*64+dh)][L]
    const void* __restrict__ mask, const int* __restrict__ mode_p,
    __hip_bfloat16* __restrict__ Og) {
  __shared__ __hip_bfloat16 Kl[64][72];
  __shared__ __hip_bfloat16 Vl[64][72];  // [d][kv]
  __shared__ __hip_bfloat16 Pl[4][32][72];
  __shared__ float maskb[64];

  const int tid = threadIdx.x;
  const int lane = tid & 63;
  const int w = tid >> 6;
  const int hi = lane >> 4;
  const int r16 = lane & 15;
  const int bh = blockIdx.x;
  const int b = bh >> 4;
  const int h = bh & 15;
  const int qb = blockIdx.y;
  const int mode = *mode_p;

  bf16x8 qf[2][2];
#pragma unroll
  for (int m = 0; m < 2; ++m)
#pragma unroll
    for (int ks = 0; ks < 2; ++ks) {
      const int q = qb * 128 + w * 32 + m * 16 + r16;
      qf[m][ks] = *reinterpret_cast<const bf16x8*>(
          &Qg[(size_t)(b * L_ + q) * D_ + h * DH_ + ks * 32 + hi * 8]);
    }

  float mrun[2][4], lrun[2][4];
  f32x4 o[2][4];
#pragma unroll
  for (int m = 0; m < 2; ++m)
#pragma unroll
    for (int r = 0; r < 4; ++r) { mrun[m][r] = -1e30f; lrun[m][r] = 0.f; }
#pragma unroll
  for (int m = 0; m < 2; ++m)
#pragma unroll
    for (int n = 0; n < 4; ++n) o[m][n] = (f32x4){0.f, 0.f, 0.f, 0.f};

  const int srow = tid >> 3;        // 0..31
  const int scol = (tid & 7) * 8;   // 0..56

  for (int kv0 = 0; kv0 < L_; kv0 += 64) {
    __syncthreads();
#pragma unroll
    for (int p = 0; p < 2; ++p) {
      const int r = srow + p * 32;
      int4 kvec = *reinterpret_cast<const int4*>(
          &Kg[(size_t)(b * L_ + kv0 + r) * D_ + h * DH_ + scol]);
      *reinterpret_cast<int4*>(&Kl[r][scol]) = kvec;
      int4 vvec = *reinterpret_cast<const int4*>(
          &VTg[(size_t)(b * D_ + h * DH_ + r) * L_ + kv0 + scol]);
      *reinterpret_cast<int4*>(&Vl[r][scol]) = vvec;
    }
    if (tid < 64) {
      const size_t mi = (size_t)b * L_ + kv0 + tid;
      bool mk;
      if (mode == 0)      mk = reinterpret_cast<const float*>(mask)[mi] != 0.f;
      else if (mode == 1) mk = reinterpret_cast<const int*>(mask)[mi] != 0;
      else                mk = reinterpret_cast<const unsigned char*>(mask)[mi] != 0;
      maskb[tid] = mk ? 1.f : 0.f;
    }
    __syncthreads();

    // S = Q K^T / 8, masked
    float s[2][4][4];
#pragma unroll
    for (int m = 0; m < 2; ++m) {
#pragma unroll
      for (int n = 0; n < 4; ++n) {
        f32x4 sa = (f32x4){0.f, 0.f, 0.f, 0.f};
#pragma unroll
        for (int ks = 0; ks < 2; ++ks) {
          bf16x8 kf = *reinterpret_cast<const bf16x8*>(
              &Kl[n * 16 + r16][ks * 32 + hi * 8]);
          sa = __builtin_amdgcn_mfma_f32_16x16x32_bf16(qf[m][ks], kf, sa, 0, 0, 0);
        }
        const float mb = maskb[n * 16 + r16];
#pragma unroll
        for (int r = 0; r < 4; ++r)
          s[m][n][r] = (mb != 0.f) ? -1e12f : sa[r] * 0.125f;
      }
    }

    // online softmax (rows live in 16-lane groups)
#pragma unroll
    for (int m = 0; m < 2; ++m) {
#pragma unroll
      for (int r = 0; r < 4; ++r) {
        float rm = fmaxf(fmaxf(s[m][0][r], s[m][1][r]),
                         fmaxf(s[m][2][r], s[m][3][r]));
#pragma unroll
        for (int off = 1; off < 16; off <<= 1)
          rm = fmaxf(rm, __shfl_xor(rm, off, 16));
        const float mn = fmaxf(mrun[m][r], rm);
        const float corr = __expf(mrun[m][r] - mn);
        mrun[m][r] = mn;
        float ps = 0.f;
#pragma unroll
        for (int n = 0; n < 4; ++n) {
          const float p = __expf(s[m][n][r] - mn);
          s[m][n][r] = p;
          ps += p;
        }
#pragma unroll
        for (int off = 1; off < 16; off <<= 1)
          ps += __shfl_xor(ps, off, 16);
        lrun[m][r] = lrun[m][r] * corr + ps;
#pragma unroll
        for (int nd = 0; nd < 4; ++nd) o[m][nd][r] *= corr;
      }
    }

    // P -> LDS (per-wave buffer, no block sync needed)
#pragma unroll
    for (int m = 0; m < 2; ++m)
#pragma unroll
      for (int n = 0; n < 4; ++n)
#pragma unroll
        for (int r = 0; r < 4; ++r)
          Pl[w][m * 16 + hi * 4 + r][n * 16 + r16] = __float2bfloat16(s[m][n][r]);

    // O += P V
#pragma unroll
    for (int m = 0; m < 2; ++m)
#pragma unroll
      for (int nd = 0; nd < 4; ++nd)
#pragma unroll
        for (int ks = 0; ks < 2; ++ks) {
          bf16x8 pa = *reinterpret_cast<const bf16x8*>(
              &Pl[w][m * 16 + r16][ks * 32 + hi * 8]);
          bf16x8 vb = *reinterpret_cast<const bf16x8*>(
              &Vl[nd * 16 + r16][ks * 32 + hi * 8]);
          o[m][nd] = __builtin_amdgcn_mfma_f32_16x16x32_bf16(pa, vb, o[m][nd], 0, 0, 0);
        }
  }

#pragma unroll
  for (int m = 0; m < 2; ++m)
#pragma unroll
    for (int r = 0; r < 4; ++r) {
      const float inv = 1.f / lrun[m][r];
      const int q = qb * 128 + w * 32 + m * 16 + hi * 4 + r;
#pragma unroll
      for (int nd = 0; nd < 4; ++nd)
        Og[(size_t)(b * L_ + q) * D_ + h * DH_ + nd * 16 + r16] =
            __float2bfloat16(o[m][nd][r] * inv);
    }
}

// ---------------- LayerNorm (row=1024), optional bf16 copy ----------------
__global__ __launch_bounds__(256) void layernorm_kernel(
    const float* __restrict__ in, const float* __restrict__ g,
    const float* __restrict__ be, float* __restrict__ outf,
    __hip_bfloat16* __restrict__ outb) {
  const int row = blockIdx.x;
  const int tid = threadIdx.x;
  const float4 v = reinterpret_cast<const float4*>(in + (size_t)row * D_)[tid];
  float s = v.x + v.y + v.z + v.w;
  float ss = v.x * v.x + v.y * v.y + v.z * v.z + v.w * v.w;
#pragma unroll
  for (int off = 1; off < 64; off <<= 1) {
    s += __shfl_xor(s, off, 64);
    ss += __shfl_xor(ss, off, 64);
  }
  __shared__ float red[8];
  const int w = tid >> 6, lane = tid & 63;
  if (lane == 0) { red[w] = s; red[4 + w] = ss; }
  __syncthreads();
  s = red[0] + red[1] + red[2] + red[3];
  ss = red[4] + red[5] + red[6] + red[7];
  const float mu = s * (1.f / D_);
  const float rs = rsqrtf(ss * (1.f / D_) - mu * mu + 1e-5f);
  const float4 gv = reinterpret_cast<const float4*>(g)[tid];
  const float4 bv = reinterpret_cast<const float4*>(be)[tid];
  float4 ov;
  ov.x = (v.x - mu) * rs * gv.x + bv.x;
  ov.y = (v.y - mu) * rs * gv.y + bv.y;
  ov.z = (v.z - mu) * rs * gv.z + bv.z;
  ov.w = (v.w - mu) * rs * gv.w + bv.w;
  reinterpret_cast<float4*>(outf + (size_t)row * D_)[tid] = ov;
  if (outb) {
    __hip_bfloat16 t[4] = {__float2bfloat16(ov.x), __float2bfloat16(ov.y),
                           __float2bfloat16(ov.z), __float2bfloat16(ov.w)};
    *reinterpret_cast<uint2*>(&outb[(size_t)row * D_ + tid * 4]) =
        *reinterpret_cast<const uint2*>(t);
  }
}

// ---------------- launch ----------------
extern "C" void kernel_launch(void* const* d_in, const int* in_sizes, int n_in,
                              void* d_out, int out_size, void* d_ws,
                              size_t ws_size, hipStream_t stream) {
  (void)in_sizes; (void)n_in; (void)out_size; (void)ws_size;
  const float* x   = (const float*)d_in[0];
  const void*  msk = d_in[1];
  const float* wq  = (const float*)d_in[2];
  const float* bq  = (const float*)d_in[3];
  const float* wk  = (const float*)d_in[4];
  const float* bk  = (const float*)d_in[5];
  const float* wv  = (const float*)d_in[6];
  const float* bv  = (const float*)d_in[7];
  const float* wo  = (const float*)d_in[8];
  const float* bo  = (const float*)d_in[9];
  const float* w1  = (const float*)d_in[10];
  const float* b1  = (const float*)d_in[11];
  const float* w2  = (const float*)d_in[12];
  const float* b2  = (const float*)d_in[13];
  const float* g1  = (const float*)d_in[14];
  const float* be1 = (const float*)d_in[15];
  const float* g2  = (const float*)d_in[16];
  const float* be2 = (const float*)d_in[17];

  char* ws = (char*)d_ws;
  int*            MODE = (int*)(ws + 0);
  __hip_bfloat16* XB   = (__hip_bfloat16*)(ws + 256);        // x bf16; later x1 bf16
  __hip_bfloat16* WQT  = (__hip_bfloat16*)(ws + 16777472);
  __hip_bfloat16* WKT  = (__hip_bfloat16*)(ws + 18874624);
  __hip_bfloat16* WVT  = (__hip_bfloat16*)(ws + 20971776);
  __hip_bfloat16* WOT  = (__hip_bfloat16*)(ws + 23068928);
  __hip_bfloat16* W1T  = (__hip_bfloat16*)(ws + 25166080);
  __hip_bfloat16* W2T  = (__hip_bfloat16*)(ws + 33554688);
  __hip_bfloat16* QB   = (__hip_bfloat16*)(ws + 41943296);
  __hip_bfloat16* KB   = (__hip_bfloat16*)(ws + 58720512);
  __hip_bfloat16* VB   = (__hip_bfloat16*)(ws + 75497728);
  __hip_bfloat16* OB   = (__hip_bfloat16*)(ws + 92274944);
  __hip_bfloat16* HB   = QB;  // FF hidden [8192][4096] reuses QKV+O region
  __hip_bfloat16* VT   = (__hip_bfloat16*)(ws + 109052160);
  float*          R1   = (float*)(ws + 125829376);
  float*          OUT  = (float*)d_out;

  mask_mode_detect<<<1, 256, 0, stream>>>((const unsigned int*)msk, MODE);
  cvt_f32_bf16<<<(M_ * D_ / 4 + 255) / 256, 256, 0, stream>>>(
      (const float4*)x, (ushort4*)XB, M_ * D_ / 4);

  dim3 tb(32, 8);
  transpose_cvt<<<dim3(D_ / 32, D_ / 32), tb, 0, stream>>>(wq, WQT, D_, D_);
  transpose_cvt<<<dim3(D_ / 32, D_ / 32), tb, 0, stream>>>(wk, WKT, D_, D_);
  transpose_cvt<<<dim3(D_ / 32, D_ / 32), tb, 0, stream>>>(wv, WVT, D_, D_);
  transpose_cvt<<<dim3(D_ / 32, D_ / 32), tb, 0, stream>>>(wo, WOT, D_, D_);
  transpose_cvt<<<dim3(DFF_ / 32, D_ / 32), tb, 0, stream>>>(w1, W1T, D_, DFF_);
  transpose_cvt<<<dim3(D_ / 32, DFF_ / 32), tb, 0, stream>>>(w2, W2T, DFF_, D_);

  gemm_bt<0><<<dim3(M_ / 128, D_ / 128), 256, 0, stream>>>(XB, WQT, bq, nullptr, QB, M_, D_, D_);
  gemm_bt<0><<<dim3(M_ / 128, D_ / 128), 256, 0, stream>>>(XB, WKT, bk, nullptr, KB, M_, D_, D_);
  gemm_bt<0><<<dim3(M_ / 128, D_ / 128), 256, 0, stream>>>(XB, WVT, bv, nullptr, VB, M_, D_, D_);

  transpose_v<<<dim3(L_ / 32, D_ / 32, B_), tb, 0, stream>>>(VB, VT);
  attn_kernel<<<dim3(B_ * H_, L_ / 128), 256, 0, stream>>>(QB, KB, VT, msk, MODE, OB);

  gemm_bt<2><<<dim3(M_ / 128, D_ / 128), 256, 0, stream>>>(OB, WOT, bo, x, R1, M_, D_, D_);
  layernorm_kernel<<<M_, 256, 0, stream>>>(R1, g1, be1, R1, XB);
  gemm_bt<1><<<dim3(M_ / 128, DFF_ / 128), 256, 0, stream>>>(XB, W1T, b1, nullptr, HB, M_, DFF_, D_);
  gemm_bt<2><<<dim3(M_ / 128, D_ / 128), 256, 0, stream>>>(HB, W2T, b2, R1, OUT, M_, D_, DFF_);
  layernorm_kernel<<<M_, 256, 0, stream>>>(OUT, g2, be2, OUT, nullptr);
}

// Round 2
// 529.453 us; speedup vs baseline: 1.1705x; 1.1705x over previous
//
#include <hip/hip_runtime.h>
#include <hip/hip_bf16.h>

#define B_   4
#define L_   2048
#define D_   1024
#define H_   16
#define DH_  64
#define DFF_ 4096
#define M_   (B_ * L_)   // 8192

typedef __attribute__((ext_vector_type(8))) short bf16x8;
typedef __attribute__((ext_vector_type(4))) float f32x4;

#define GLOAD16(gp, lp)                                                       \
  __builtin_amdgcn_global_load_lds(                                           \
      (const __attribute__((address_space(1))) unsigned int*)(gp),            \
      (__attribute__((address_space(3))) unsigned int*)(lp), 16, 0, 0)

// ---------------- mask storage-width detection ----------------
__global__ void mask_mode_detect(const unsigned int* __restrict__ m,
                                 int* __restrict__ mode) {
  __shared__ int flags[2];
  if (threadIdx.x < 2) flags[threadIdx.x] = 0;
  __syncthreads();
  int nf32 = 0, n01 = 0;
  for (int i = threadIdx.x; i < 2048; i += 256) {
    unsigned w = m[i];
    if (w != 0u && w != 0x3f800000u) nf32 = 1;
    if (w > 1u) n01 = 1;
  }
  if (nf32) atomicOr(&flags[0], 1);
  if (n01)  atomicOr(&flags[1], 1);
  __syncthreads();
  if (threadIdx.x == 0)
    *mode = (!flags[0]) ? 0 : ((!flags[1]) ? 1 : 2);  // 0=f32 1=i32 2=u8
}

// ---------------- mask -> additive f32 (-1e12 masked, 0 keep) -------------
__global__ void mask_prep(const void* __restrict__ m,
                          const int* __restrict__ mode_p,
                          float* __restrict__ out, int n) {
  int i = blockIdx.x * 256 + threadIdx.x;
  if (i >= n) return;
  int mode = *mode_p;
  bool mk;
  if (mode == 0)      mk = reinterpret_cast<const float*>(m)[i] != 0.f;
  else if (mode == 1) mk = reinterpret_cast<const int*>(m)[i] != 0;
  else                mk = reinterpret_cast<const unsigned char*>(m)[i] != 0;
  out[i] = mk ? -1e12f : 0.f;
}

// ---------------- f32 -> bf16 convert (vectorized) ----------------
__global__ void cvt_f32_bf16(const float4* __restrict__ in,
                             ushort4* __restrict__ out, int n4) {
  int i = blockIdx.x * 256 + threadIdx.x;
  if (i >= n4) return;
  float4 v = in[i];
  __hip_bfloat16 a = __float2bfloat16(v.x);
  __hip_bfloat16 b = __float2bfloat16(v.y);
  __hip_bfloat16 c = __float2bfloat16(v.z);
  __hip_bfloat16 d = __float2bfloat16(v.w);
  ushort4 o;
  o.x = *reinterpret_cast<unsigned short*>(&a);
  o.y = *reinterpret_cast<unsigned short*>(&b);
  o.z = *reinterpret_cast<unsigned short*>(&c);
  o.w = *reinterpret_cast<unsigned short*>(&d);
  out[i] = o;
}

// ---------------- W[K][N] f32 -> Wt[N][K] bf16 ----------------
__global__ void transpose_cvt(const float* __restrict__ W,
                              __hip_bfloat16* __restrict__ Wt, int K, int N) {
  __shared__ float t[32][33];
  const int n0 = blockIdx.x * 32, k0 = blockIdx.y * 32;
  const int tx = threadIdx.x, ty = threadIdx.y;  // 32x8
#pragma unroll
  for (int i = 0; i < 4; ++i)
    t[ty + i * 8][tx] = W[(size_t)(k0 + ty + i * 8) * N + n0 + tx];
  __syncthreads();
#pragma unroll
  for (int i = 0; i < 4; ++i)
    Wt[(size_t)(n0 + ty + i * 8) * K + k0 + tx] =
        __float2bfloat16(t[tx][ty + i * 8]);
}

// ---------------- V[b*L+l][D] bf16 -> VT[(b*D+d)][L] bf16 ----------------
__global__ void transpose_v(const __hip_bfloat16* __restrict__ Vin,
                            __hip_bfloat16* __restrict__ Vt) {
  __shared__ __hip_bfloat16 t[32][33];
  const int l0 = blockIdx.x * 32, d0 = blockIdx.y * 32, b = blockIdx.z;
  const int tx = threadIdx.x, ty = threadIdx.y;
#pragma unroll
  for (int i = 0; i < 4; ++i)
    t[ty + i * 8][tx] = Vin[(size_t)(b * L_ + l0 + ty + i * 8) * D_ + d0 + tx];
  __syncthreads();
#pragma unroll
  for (int i = 0; i < 4; ++i) {
    int d = d0 + ty + i * 8;
    Vt[(size_t)(b * D_ + d) * L_ + l0 + tx] = t[tx][ty + i * 8];
  }
}

// ---------------- GEMM (m97 structure): C = A * Bt^T + bias ---------------
// 128x128 tile, BK=32, global_load_lds w=16, source-swizzled linear LDS.
// EP 0: bf16 out=acc+bias; EP 1: bf16 out=relu(acc+bias); EP 2: f32 out=acc+bias+res
template <int EP>
__global__ __launch_bounds__(256) void gemm_bt(
    const __hip_bfloat16* __restrict__ A, const __hip_bfloat16* __restrict__ Bt,
    const float* __restrict__ bias, const float* __restrict__ res,
    void* __restrict__ out, int M, int N, int K) {
  __shared__ __align__(16) char As[128 * 64];  // [128][32] bf16 linear
  __shared__ __align__(16) char Bs[128 * 64];
  const int tid = threadIdx.x;
  const int lane = tid & 63;
  const int w = tid >> 6;
  const int wm = w >> 1, wn = w & 1;
  const int bm = blockIdx.x * 128;
  const int bn = blockIdx.y * 128;
  const int r16 = lane & 15;
  const int hi = lane >> 4;

  f32x4 acc[4][4];
#pragma unroll
  for (int m = 0; m < 4; ++m)
#pragma unroll
    for (int n = 0; n < 4; ++n) acc[m][n] = (f32x4){0.f, 0.f, 0.f, 0.f};

  for (int k0 = 0; k0 < K; k0 += 32) {
    __syncthreads();
#pragma unroll
    for (int c = 0; c < 2; ++c) {
      const int seg = c * 256 + tid;
      const int row = seg >> 2;                  // 0..127
      const int csl = (seg & 3) ^ (row & 3);     // source swizzle (16B slots)
      GLOAD16(&A[(size_t)(bm + row) * K + k0 + csl * 8],
              As + (c * 256 + w * 64) * 16);
      GLOAD16(&Bt[(size_t)(bn + row) * K + k0 + csl * 8],
              Bs + (c * 256 + w * 64) * 16);
    }
    __syncthreads();

    bf16x8 af[4], bfr[4];
#pragma unroll
    for (int m = 0; m < 4; ++m) {
      const int arow = wm * 64 + m * 16 + r16;
      af[m] = *reinterpret_cast<const bf16x8*>(
          As + arow * 64 + ((hi * 16) ^ ((arow & 3) << 4)));
    }
#pragma unroll
    for (int n = 0; n < 4; ++n) {
      const int brow = wn * 64 + n * 16 + r16;
      bfr[n] = *reinterpret_cast<const bf16x8*>(
          Bs + brow * 64 + ((hi * 16) ^ ((brow & 3) << 4)));
    }
#pragma unroll
    for (int m = 0; m < 4; ++m)
#pragma unroll
      for (int n = 0; n < 4; ++n)
        acc[m][n] = __builtin_amdgcn_mfma_f32_16x16x32_bf16(af[m], bfr[n],
                                                            acc[m][n], 0, 0, 0);
  }

  const int rg = hi * 4;
#pragma unroll
  for (int m = 0; m < 4; ++m) {
#pragma unroll
    for (int n = 0; n < 4; ++n) {
      const int col = bn + wn * 64 + n * 16 + r16;
      const float bv = bias[col];
#pragma unroll
      for (int r = 0; r < 4; ++r) {
        const int row = bm + wm * 64 + m * 16 + rg + r;
        const size_t idx = (size_t)row * N + col;
        float v = acc[m][n][r] + bv;
        if (EP == 0) {
          ((__hip_bfloat16*)out)[idx] = __float2bfloat16(v);
        } else if (EP == 1) {
          ((__hip_bfloat16*)out)[idx] = __float2bfloat16(v > 0.f ? v : 0.f);
        } else {
          ((float*)out)[idx] = v + res[idx];
        }
      }
    }
  }
}

// ---------------- flash attention (swapped QK^T, swizzled LDS) -------------
// grid: (B*H, L/128); block 256 = 4 waves; wave owns 32 q rows; KV tile 64.
// S^T = mfma(K_frag, Q_frag): lane holds q = lane&15 (+16m), k = n*16+hi*4+r.
__global__ __launch_bounds__(256) void attn_kernel(
    const __hip_bfloat16* __restrict__ Qg, const __hip_bfloat16* __restrict__ Kg,
    const __hip_bfloat16* __restrict__ VTg,  // [(b*D + h*64+dh)][L]
    const float* __restrict__ maskf,         // [B*L] additive (-1e12 / 0)
    __hip_bfloat16* __restrict__ Og) {
  __shared__ __align__(16) char Kl[64 * 128];   // [kv][d], swizzled
  __shared__ __align__(16) char Vl[64 * 128];   // [dh][kv], swizzled
  __shared__ __align__(16) char Pl[4][32 * 128];// per-wave [q][k], swizzled
  __shared__ float maskb[64];

  const int tid = threadIdx.x;
  const int lane = tid & 63;
  const int w = tid >> 6;
  const int hi = lane >> 4;
  const int r16 = lane & 15;
  const int swz = (r16 & 7) << 4;
  const int b = blockIdx.x >> 4;
  const int h = blockIdx.x & 15;
  const int qb = blockIdx.y;
  const int qbase = qb * 128 + w * 32;

  // Q fragments (B-operand): lane holds Q[q = qbase+m*16+r16][d = ks*32+hi*8+j]
  bf16x8 qf[2][2];
#pragma unroll
  for (int m = 0; m < 2; ++m)
#pragma unroll
    for (int ks = 0; ks < 2; ++ks)
      qf[m][ks] = *reinterpret_cast<const bf16x8*>(
          &Qg[(size_t)(b * L_ + qbase + m * 16 + r16) * D_ + h * DH_ +
              ks * 32 + hi * 8]);

  float mrun[2] = {-1e30f, -1e30f};
  float lrun[2] = {0.f, 0.f};
  f32x4 o[2][4];
#pragma unroll
  for (int m = 0; m < 2; ++m)
#pragma unroll
    for (int nd = 0; nd < 4; ++nd) o[m][nd] = (f32x4){0.f, 0.f, 0.f, 0.f};

  char* const Plw = Pl[w];

  for (int kv0 = 0; kv0 < L_; kv0 += 64) {
    __syncthreads();
    // stage K [64 kv][64 d] and V^T [64 dh][64 kv]: linear dest,
    // inverse-swizzled source (16B slot ^ (row&7)), swizzled reads.
#pragma unroll
    for (int c = 0; c < 2; ++c) {
      const int seg = c * 256 + tid;
      const int row = seg >> 3;                 // 0..63
      const int csl = (seg & 7) ^ (row & 7);
      GLOAD16(&Kg[(size_t)(b * L_ + kv0 + row) * D_ + h * DH_ + csl * 8],
              Kl + (c * 256 + w * 64) * 16);
      GLOAD16(&VTg[(size_t)(b * D_ + h * DH_ + row) * L_ + kv0 + csl * 8],
              Vl + (c * 256 + w * 64) * 16);
    }
    if (tid < 64) maskb[tid] = maskf[(size_t)b * L_ + kv0 + tid];
    __syncthreads();

    // S^T tiles: sacc[m][n], lane q = m*16+r16, k = n*16+hi*4+r
    f32x4 sacc[2][4];
#pragma unroll
    for (int m = 0; m < 2; ++m)
#pragma unroll
      for (int n = 0; n < 4; ++n) sacc[m][n] = (f32x4){0.f, 0.f, 0.f, 0.f};
#pragma unroll
    for (int n = 0; n < 4; ++n) {
      const int krow = n * 16 + r16;
#pragma unroll
      for (int ks = 0; ks < 2; ++ks) {
        const bf16x8 kf = *reinterpret_cast<const bf16x8*>(
            Kl + krow * 128 + ((ks * 64 + hi * 16) ^ swz));
#pragma unroll
        for (int m = 0; m < 2; ++m)
          sacc[m][n] = __builtin_amdgcn_mfma_f32_16x16x32_bf16(
              kf, qf[m][ks], sacc[m][n], 0, 0, 0);
      }
    }

    float p[2][4][4];
#pragma unroll
    for (int m = 0; m < 2; ++m)
#pragma unroll
      for (int n = 0; n < 4; ++n) {
        const float4 mv = *reinterpret_cast<const float4*>(&maskb[n * 16 + hi * 4]);
        p[m][n][0] = sacc[m][n][0] * 0.125f + mv.x;
        p[m][n][1] = sacc[m][n][1] * 0.125f + mv.y;
        p[m][n][2] = sacc[m][n][2] * 0.125f + mv.z;
        p[m][n][3] = sacc[m][n][3] * 0.125f + mv.w;
      }

    // online softmax: one q-row per lane per m
#pragma unroll
    for (int m = 0; m < 2; ++m) {
      float lm = p[m][0][0];
#pragma unroll
      for (int n = 0; n < 4; ++n)
#pragma unroll
        for (int r = 0; r < 4; ++r) lm = fmaxf(lm, p[m][n][r]);
      lm = fmaxf(lm, __shfl_xor(lm, 16, 64));
      lm = fmaxf(lm, __shfl_xor(lm, 32, 64));
      const float mn = fmaxf(mrun[m], lm);
      const float corr = __expf(mrun[m] - mn);
      mrun[m] = mn;
      float ls = 0.f;
#pragma unroll
      for (int n = 0; n < 4; ++n)
#pragma unroll
        for (int r = 0; r < 4; ++r) {
          const float e = __expf(p[m][n][r] - mn);
          p[m][n][r] = e;
          ls += e;
        }
      ls += __shfl_xor(ls, 16, 64);
      ls += __shfl_xor(ls, 32, 64);
      lrun[m] = lrun[m] * corr + ls;
      // broadcast corr to the lanes holding this q-row's O entries
      float crs[4];
#pragma unroll
      for (int r = 0; r < 4; ++r)
        crs[r] = __shfl(corr, (lane & 48) | (hi * 4 + r), 64);
#pragma unroll
      for (int nd = 0; nd < 4; ++nd)
#pragma unroll
        for (int r = 0; r < 4; ++r) o[m][nd][r] *= crs[r];
    }

    // P -> per-wave LDS (packed b64 writes, swizzled)
#pragma unroll
    for (int m = 0; m < 2; ++m) {
      const int prow = m * 16 + r16;
#pragma unroll
      for (int n = 0; n < 4; ++n) {
        union { unsigned long long u; unsigned short us[4]; } pk;
#pragma unroll
        for (int r = 0; r < 4; ++r) {
          __hip_bfloat16 t = __float2bfloat16(p[m][n][r]);
          pk.us[r] = *reinterpret_cast<unsigned short*>(&t);
        }
        *reinterpret_cast<unsigned long long*>(
            Plw + prow * 128 + ((n * 32 + hi * 8) ^ swz)) = pk.u;
      }
    }

    // O += P V
    bf16x8 pa[2][2];
#pragma unroll
    for (int m = 0; m < 2; ++m)
#pragma unroll
      for (int ks = 0; ks < 2; ++ks)
        pa[m][ks] = *reinterpret_cast<const bf16x8*>(
            Plw + (m * 16 + r16) * 128 + ((ks * 64 + hi * 16) ^ swz));
#pragma unroll
    for (int nd = 0; nd < 4; ++nd) {
      const int vrow = nd * 16 + r16;
#pragma unroll
      for (int ks = 0; ks < 2; ++ks) {
        const bf16x8 vb = *reinterpret_cast<const bf16x8*>(
            Vl + vrow * 128 + ((ks * 64 + hi * 16) ^ swz));
#pragma unroll
        for (int m = 0; m < 2; ++m)
          o[m][nd] = __builtin_amdgcn_mfma_f32_16x16x32_bf16(pa[m][ks], vb,
                                                             o[m][nd], 0, 0, 0);
      }
    }
  }

  // epilogue: normalize rows and store
#pragma unroll
  for (int m = 0; m < 2; ++m) {
    const float inv = 1.f / lrun[m];
    float invr[4];
#pragma unroll
    for (int r = 0; r < 4; ++r)
      invr[r] = __shfl(inv, (lane & 48) | (hi * 4 + r), 64);
#pragma unroll
    for (int r = 0; r < 4; ++r) {
      const int q = qbase + m * 16 + hi * 4 + r;
#pragma unroll
      for (int nd = 0; nd < 4; ++nd)
        Og[(size_t)(b * L_ + q) * D_ + h * DH_ + nd * 16 + r16] =
            __float2bfloat16(o[m][nd][r] * invr[r]);
    }
  }
}

// ---------------- LayerNorm (row=1024), optional bf16 copy ----------------
__global__ __launch_bounds__(256) void layernorm_kernel(
    const float* __restrict__ in, const float* __restrict__ g,
    const float* __restrict__ be, float* __restrict__ outf,
    __hip_bfloat16* __restrict__ outb) {
  const int row = blockIdx.x;
  const int tid = threadIdx.x;
  const float4 v = reinterpret_cast<const float4*>(in + (size_t)row * D_)[tid];
  float s = v.x + v.y + v.z + v.w;
  float ss = v.x * v.x + v.y * v.y + v.z * v.z + v.w * v.w;
#pragma unroll
  for (int off = 1; off < 64; off <<= 1) {
    s += __shfl_xor(s, off, 64);
    ss += __shfl_xor(ss, off, 64);
  }
  __shared__ float red[8];
  const int w = tid >> 6, lane = tid & 63;
  if (lane == 0) { red[w] = s; red[4 + w] = ss; }
  __syncthreads();
  s = red[0] + red[1] + red[2] + red[3];
  ss = red[4] + red[5] + red[6] + red[7];
  const float mu = s * (1.f / D_);
  const float rs = rsqrtf(ss * (1.f / D_) - mu * mu + 1e-5f);
  const float4 gv = reinterpret_cast<const float4*>(g)[tid];
  const float4 bv = reinterpret_cast<const float4*>(be)[tid];
  float4 ov;
  ov.x = (v.x - mu) * rs * gv.x + bv.x;
  ov.y = (v.y - mu) * rs * gv.y + bv.y;
  ov.z = (v.z - mu) * rs * gv.z + bv.z;
  ov.w = (v.w - mu) * rs * gv.w + bv.w;
  reinterpret_cast<float4*>(outf + (size_t)row * D_)[tid] = ov;
  if (outb) {
    __hip_bfloat16 t[4] = {__float2bfloat16(ov.x), __float2bfloat16(ov.y),
                           __float2bfloat16(ov.z), __float2bfloat16(ov.w)};
    *reinterpret_cast<uint2*>(&outb[(size_t)row * D_ + tid * 4]) =
        *reinterpret_cast<const uint2*>(t);
  }
}

// ---------------- launch ----------------
extern "C" void kernel_launch(void* const* d_in, const int* in_sizes, int n_in,
                              void* d_out, int out_size, void* d_ws,
                              size_t ws_size, hipStream_t stream) {
  (void)in_sizes; (void)n_in; (void)out_size; (void)ws_size;
  const float* x   = (const float*)d_in[0];
  const void*  msk = d_in[1];
  const float* wq  = (const float*)d_in[2];
  const float* bq  = (const float*)d_in[3];
  const float* wk  = (const float*)d_in[4];
  const float* bk  = (const float*)d_in[5];
  const float* wv  = (const float*)d_in[6];
  const float* bv  = (const float*)d_in[7];
  const float* wo  = (const float*)d_in[8];
  const float* bo  = (const float*)d_in[9];
  const float* w1  = (const float*)d_in[10];
  const float* b1  = (const float*)d_in[11];
  const float* w2  = (const float*)d_in[12];
  const float* b2  = (const float*)d_in[13];
  const float* g1  = (const float*)d_in[14];
  const float* be1 = (const float*)d_in[15];
  const float* g2  = (const float*)d_in[16];
  const float* be2 = (const float*)d_in[17];

  char* ws = (char*)d_ws;
  int*            MODE  = (int*)(ws + 0);
  float*          MASKF = (float*)(ws + 256);                 // 32 KB
  __hip_bfloat16* XB    = (__hip_bfloat16*)(ws + 65536);      // 16 MB
  __hip_bfloat16* WQT   = (__hip_bfloat16*)(ws + 16842752);
  __hip_bfloat16* WKT   = (__hip_bfloat16*)(ws + 18939904);
  __hip_bfloat16* WVT   = (__hip_bfloat16*)(ws + 21037056);
  __hip_bfloat16* WOT   = (__hip_bfloat16*)(ws + 23134208);
  __hip_bfloat16* W1T   = (__hip_bfloat16*)(ws + 25231360);   // 8 MB
  __hip_bfloat16* W2T   = (__hip_bfloat16*)(ws + 33619968);   // 8 MB
  __hip_bfloat16* QB    = (__hip_bfloat16*)(ws + 42008576);   // 16 MB
  __hip_bfloat16* KB    = (__hip_bfloat16*)(ws + 58785792);
  __hip_bfloat16* VB    = (__hip_bfloat16*)(ws + 75563008);
  __hip_bfloat16* OB    = (__hip_bfloat16*)(ws + 92340224);
  __hip_bfloat16* HB    = QB;  // FF hidden [8192][4096] reuses QKV+O (64 MB)
  __hip_bfloat16* VT    = (__hip_bfloat16*)(ws + 109117440);  // 16 MB
  float*          R1    = (float*)(ws + 125894656);           // 32 MB
  float*          OUT   = (float*)d_out;

  mask_mode_detect<<<1, 256, 0, stream>>>((const unsigned int*)msk, MODE);
  mask_prep<<<(B_ * L_ + 255) / 256, 256, 0, stream>>>(msk, MODE, MASKF, B_ * L_);
  cvt_f32_bf16<<<(M_ * D_ / 4 + 255) / 256, 256, 0, stream>>>(
      (const float4*)x, (ushort4*)XB, M_ * D_ / 4);

  dim3 tb(32, 8);
  transpose_cvt<<<dim3(D_ / 32, D_ / 32), tb, 0, stream>>>(wq, WQT, D_, D_);
  transpose_cvt<<<dim3(D_ / 32, D_ / 32), tb, 0, stream>>>(wk, WKT, D_, D_);
  transpose_cvt<<<dim3(D_ / 32, D_ / 32), tb, 0, stream>>>(wv, WVT, D_, D_);
  transpose_cvt<<<dim3(D_ / 32, D_ / 32), tb, 0, stream>>>(wo, WOT, D_, D_);
  transpose_cvt<<<dim3(DFF_ / 32, D_ / 32), tb, 0, stream>>>(w1, W1T, D_, DFF_);
  transpose_cvt<<<dim3(D_ / 32, DFF_ / 32), tb, 0, stream>>>(w2, W2T, DFF_, D_);

  gemm_bt<0><<<dim3(M_ / 128, D_ / 128), 256, 0, stream>>>(XB, WQT, bq, nullptr, QB, M_, D_, D_);
  gemm_bt<0><<<dim3(M_ / 128, D_ / 128), 256, 0, stream>>>(XB, WKT, bk, nullptr, KB, M_, D_, D_);
  gemm_bt<0><<<dim3(M_ / 128, D_ / 128), 256, 0, stream>>>(XB, WVT, bv, nullptr, VB, M_, D_, D_);

  transpose_v<<<dim3(L_ / 32, D_ / 32, B_), tb, 0, stream>>>(VB, VT);
  attn_kernel<<<dim3(B_ * H_, L_ / 128), 256, 0, stream>>>(QB, KB, VT, MASKF, OB);

  gemm_bt<2><<<dim3(M_ / 128, D_ / 128), 256, 0, stream>>>(OB, WOT, bo, x, R1, M_, D_, D_);
  layernorm_kernel<<<M_, 256, 0, stream>>>(R1, g1, be1, R1, XB);
  gemm_bt<1><<<dim3(M_ / 128, DFF_ / 128), 256, 0, stream>>>(XB, W1T, b1, nullptr, HB, M_, DFF_, D_);
  gemm_bt<2><<<dim3(M_ / 128, D_ / 128), 256, 0, stream>>>(HB, W2T, b2, R1, OUT, M_, D_, DFF_);
  layernorm_kernel<<<M_, 256, 0, stream>>>(OUT, g2, be2, OUT, nullptr);
}